// Round 3
// baseline (396.793 us; speedup 1.0000x reference)
//
#include <hip/hip_runtime.h>

// GatedMoE on MI355X (gfx950), fp16 MFMA path, round 3.
// Changes vs r2: double-buffered LDS with raw s_barrier + manual s_waitcnt vmcnt(N)
// (AITER-style pipeline: wait only on loads issued one full iteration ago);
// LDS-free vectorized transpose-convert (coalesced column reads, half8 writes).

typedef _Float16 half8 __attribute__((ext_vector_type(8)));
typedef _Float16 half4t __attribute__((ext_vector_type(4)));
typedef float f4 __attribute__((ext_vector_type(4)));

#define N_TOK 4096
#define DDIM  768
#define HDIM  2048
#define NEXP  8
#define CAP   614   // int(1.2 * 4096 / 8)
#define CAPP  640

// ---- workspace layout (bytes) ----
#define XH_OFF    0L           // (4097*768) fp16
#define W1T_OFF   6292992L     // [8][4096][768] fp16
#define W2T_OFF   56624640L    // [8][768][2048] fp16
#define ACT_OFF   81790464L    // [16][640][2048] fp16
#define YBUF_OFF  123733504L   // [16][640][768] fp32
#define EIDX_OFF  155190784L   // [4096][2] int
#define WTS_OFF   155223552L   // [4096][2] float
#define TOKL_OFF  155256320L   // [16][640] int
#define TOKP_OFF  155297280L   // [2][4096] int
#define CNT_OFF   155330048L   // [16] int

__device__ __forceinline__ void gld16(const void* g, void* l) {
  __builtin_amdgcn_global_load_lds(
      (const __attribute__((address_space(1))) unsigned int*)g,
      (__attribute__((address_space(3))) unsigned int*)l, 16, 0, 0);
}

#define RAW_BARRIER() asm volatile("s_barrier" ::: "memory")

// -------------------- conversions --------------------

__global__ __launch_bounds__(256) void cvt_x_kernel(const float* __restrict__ x,
                                                    _Float16* __restrict__ xh) {
  long i = (long)blockIdx.x * 256 + threadIdx.x;
  long base = i * 4;
  const long total = (long)(N_TOK + 1) * DDIM;
  if (base >= total) return;
  half4t hv;
  if (base < (long)N_TOK * DDIM) {
    f4 v = *(const f4*)(x + base);
    hv[0] = (_Float16)v[0]; hv[1] = (_Float16)v[1];
    hv[2] = (_Float16)v[2]; hv[3] = (_Float16)v[3];
  } else {
    hv[0] = hv[1] = hv[2] = hv[3] = (_Float16)0.f;
  }
  *(half4t*)(xh + base) = hv;
}

// transpose+convert, LDS-free: src fp32 [e][R][C] -> dst fp16 [e][C][R].
// 64x64 tile; lane reads 8 fp32 down a column (coalesced across lanes in c),
// writes one half8 (16B) contiguous along R.
__global__ __launch_bounds__(256) void cvt_tr_kernel(const float* __restrict__ src,
                                                     _Float16* __restrict__ dst,
                                                     int R, int C) {
  int e = blockIdx.z;
  int r0 = blockIdx.x * 64, c0 = blockIdx.y * 64;
  long sb = (long)e * R * C;
  int t = threadIdx.x;
#pragma unroll
  for (int s = 0; s < 2; s++) {
    int u = t + s * 256;
    int c = u & 63, ro = u >> 6;   // lanes consecutive in c -> coalesced reads
    const float* sp = src + sb + (long)(r0 + ro * 8) * C + c0 + c;
    half8 h;
#pragma unroll
    for (int j = 0; j < 8; j++) h[j] = (_Float16)sp[(long)j * C];
    *(half8*)(dst + sb + (long)(c0 + c) * R + r0 + ro * 8) = h;
  }
}

// -------------------- router --------------------
__global__ __launch_bounds__(256) void router_kernel(const float* __restrict__ x,
                                                     const float* __restrict__ Wg,
                                                     int* __restrict__ eidx,
                                                     float* __restrict__ wts) {
  __shared__ float wg[DDIM * NEXP];
  int t = threadIdx.x;
  for (int i = t; i < DDIM * NEXP; i += 256) wg[i] = Wg[i];
  __syncthreads();
  int w = t >> 6, lane = t & 63;
  int tok = blockIdx.x * 4 + w;
  float acc[8] = {0.f, 0.f, 0.f, 0.f, 0.f, 0.f, 0.f, 0.f};
  const float* xr = x + (long)tok * DDIM;
#pragma unroll
  for (int i = 0; i < 12; i++) {
    float xv = xr[i * 64 + lane];
    const float* wr = &wg[(i * 64 + lane) * 8];
#pragma unroll
    for (int e2 = 0; e2 < 8; e2++) acc[e2] += xv * wr[e2];
  }
#pragma unroll
  for (int e2 = 0; e2 < 8; e2++) {
    float v = acc[e2];
    v += __shfl_xor(v, 32); v += __shfl_xor(v, 16); v += __shfl_xor(v, 8);
    v += __shfl_xor(v, 4);  v += __shfl_xor(v, 2);  v += __shfl_xor(v, 1);
    acc[e2] = v;
  }
  if (lane == 0) {
    float m0 = -1e30f; int i0 = 0;
#pragma unroll
    for (int e2 = 0; e2 < 8; e2++) if (acc[e2] > m0) { m0 = acc[e2]; i0 = e2; }
    float m1 = -1e30f; int i1 = 0;
#pragma unroll
    for (int e2 = 0; e2 < 8; e2++) if (e2 != i0 && acc[e2] > m1) { m1 = acc[e2]; i1 = e2; }
    float tt = __expf(m1 - m0);
    float w0 = 1.f / (1.f + tt);
    eidx[tok * 2 + 0] = i0; eidx[tok * 2 + 1] = i1;
    wts[tok * 2 + 0] = w0;  wts[tok * 2 + 1] = 1.f - w0;
  }
}

// -------------------- capacity scan --------------------
__global__ __launch_bounds__(1024) void scan_kernel(const int* __restrict__ eidx,
                                                    int* __restrict__ toklist,
                                                    int* __restrict__ tokpos,
                                                    int* __restrict__ counts) {
  int t = threadIdx.x;
  int wid = t >> 6, lane = t & 63;
  int k = wid >> 3, e = wid & 7;
  int z = wid;
  int mye[64];
#pragma unroll
  for (int c = 0; c < 64; c++) mye[c] = eidx[(c * 64 + lane) * 2 + k];
  int base = 0;
#pragma unroll 4
  for (int c = 0; c < 64; c++) {
    int n = c * 64 + lane;
    bool pred = (mye[c] == e);
    unsigned long long mask = __ballot(pred);
    if (pred) {
      int pos = base + __popcll(mask & ((1ull << lane) - 1ull));
      if (pos < CAP) {
        toklist[z * CAPP + pos] = n;
        tokpos[k * N_TOK + n] = z * CAPP + pos;
      } else {
        tokpos[k * N_TOK + n] = -1;
      }
    }
    base += __popcll(mask);
  }
  if (lane == 0) counts[z] = (base < CAP) ? base : CAP;
}

// -------------------- GEMM1 + fused SwiGLU (double-buffered) --------------------
__global__ __launch_bounds__(256, 2) void gemm1_kernel(const _Float16* __restrict__ xh,
                                                       const _Float16* __restrict__ w1t,
                                                       const int* __restrict__ toklist,
                                                       const int* __restrict__ counts,
                                                       _Float16* __restrict__ act) {
  int i = blockIdx.x;
  int xcd = i & 7, j = i >> 3;
  int m = j % 5, ii = j / 5;
  int k = ii & 1, n = ii >> 1;
  int e = xcd, z = k * 8 + e;
  int count = counts[z];
  int m0 = m * 128;
  if (m0 >= count) return;
  int n0 = n * 128;

  __shared__ _Float16 As[2 * 128 * 32];   // 16 KB
  __shared__ _Float16 Bs[2 * 256 * 32];   // 32 KB
  __shared__ int toks[128];

  int t = threadIdx.x;
  if (t < 128) {
    int r = m0 + t;
    toks[t] = (r < count) ? toklist[z * CAPP + r] : N_TOK;
  }
  __syncthreads();

  int lane = t & 63, w = t >> 6;
  int l4 = lane >> 2, lu = lane & 3;

  const _Float16* ag[2]; _Float16* al[2][2];
#pragma unroll
  for (int s = 0; s < 2; s++) {
    int row = w * 32 + s * 16 + l4;
    int u = lu ^ ((row >> 1) & 3);
    ag[s] = xh + (long)toks[row] * DDIM + u * 8;
    al[0][s] = As + row * 32 + lu * 8;
    al[1][s] = al[0][s] + 128 * 32;
  }
  const _Float16* bg[4]; _Float16* bl[2][4];
#pragma unroll
  for (int s = 0; s < 4; s++) {
    int rb = w * 64 + s * 16 + l4;
    int u = lu ^ ((rb >> 1) & 3);
    int gr = (rb < 128) ? (n0 + rb) : (2048 + n0 + (rb - 128));
    bg[s] = w1t + ((long)e * 4096 + gr) * DDIM + u * 8;
    bl[0][s] = Bs + rb * 32 + lu * 8;
    bl[1][s] = bl[0][s] + 256 * 32;
  }

  int q = lane >> 4, m16 = lane & 15;
  int wm = w & 1, wn = w >> 1;

  f4 zero4 = {0.f, 0.f, 0.f, 0.f};
  f4 acc[4][4][2];
#pragma unroll
  for (int rt = 0; rt < 4; rt++)
#pragma unroll
    for (int ct = 0; ct < 4; ct++) { acc[rt][ct][0] = zero4; acc[rt][ct][1] = zero4; }

  // prologue: stage tile 0 into buffer 0
#pragma unroll
  for (int s = 0; s < 2; s++) { gld16(ag[s], al[0][s]); ag[s] += 32; }
#pragma unroll
  for (int s = 0; s < 4; s++) { gld16(bg[s], bl[0][s]); bg[s] += 32; }

  for (int kk = 0; kk < DDIM; kk += 32) {
    int cur = (kk >> 5) & 1, nxt = cur ^ 1;
    if (kk + 32 < DDIM) {
      // issue next tile's loads, then wait only for tiles issued >=1 iter ago
#pragma unroll
      for (int s = 0; s < 2; s++) { gld16(ag[s], al[nxt][s]); ag[s] += 32; }
#pragma unroll
      for (int s = 0; s < 4; s++) { gld16(bg[s], bl[nxt][s]); bg[s] += 32; }
      asm volatile("s_waitcnt vmcnt(6)" ::: "memory");
    } else {
      asm volatile("s_waitcnt vmcnt(0)" ::: "memory");
    }
    RAW_BARRIER();  // all waves' cur-tile loads landed

    const _Float16* Ac = As + cur * 128 * 32;
    const _Float16* Bc = Bs + cur * 256 * 32;
    half8 af[4], bf[4][2];
#pragma unroll
    for (int rt = 0; rt < 4; rt++) {
      int row = wm * 64 + rt * 16 + m16;
      af[rt] = *(const half8*)(Ac + row * 32 + (q ^ ((row >> 1) & 3)) * 8);
    }
#pragma unroll
    for (int ct = 0; ct < 4; ct++) {
      int c = wn * 64 + ct * 16 + m16;
      int sw = (q ^ ((c >> 1) & 3)) * 8;
      bf[ct][0] = *(const half8*)(Bc + c * 32 + sw);
      bf[ct][1] = *(const half8*)(Bc + (128 + c) * 32 + sw);
    }
#pragma unroll
    for (int rt = 0; rt < 4; rt++)
#pragma unroll
      for (int ct = 0; ct < 4; ct++) {
        acc[rt][ct][0] = __builtin_amdgcn_mfma_f32_16x16x32_f16(af[rt], bf[ct][0], acc[rt][ct][0], 0, 0, 0);
        acc[rt][ct][1] = __builtin_amdgcn_mfma_f32_16x16x32_f16(af[rt], bf[ct][1], acc[rt][ct][1], 0, 0, 0);
      }
    RAW_BARRIER();  // readers done before next iter overwrites this buffer
  }

  long ab = (long)z * CAPP * HDIM;
#pragma unroll
  for (int rt = 0; rt < 4; rt++)
#pragma unroll
    for (int ct = 0; ct < 4; ct++)
#pragma unroll
      for (int r = 0; r < 4; r++) {
        int row = m0 + wm * 64 + rt * 16 + q * 4 + r;
        int col = n0 + wn * 64 + ct * 16 + m16;
        float h1 = acc[rt][ct][0][r], h2 = acc[rt][ct][1][r];
        float s = h2 / (1.f + __expf(-h2));
        act[ab + (long)row * HDIM + col] = (_Float16)(h1 * s);
      }
}

// -------------------- GEMM2 (double-buffered) --------------------
__global__ __launch_bounds__(256, 2) void gemm2_kernel(const _Float16* __restrict__ act,
                                                       const _Float16* __restrict__ w2t,
                                                       const int* __restrict__ counts,
                                                       float* __restrict__ ybuf) {
  int i = blockIdx.x;
  int xcd = i & 7, j = i >> 3;
  int m = j % 5, t2 = j / 5;
  int k = t2 & 1, n = t2 >> 1;
  int e = xcd, z = k * 8 + e;
  int count = counts[z];
  int m0 = m * 128;
  if (m0 >= count) return;
  int n0 = n * 128;

  __shared__ _Float16 As[2 * 128 * 32];
  __shared__ _Float16 Bs[2 * 128 * 32];

  int t = threadIdx.x;
  int lane = t & 63, w = t >> 6;
  int l4 = lane >> 2, lu = lane & 3;

  const _Float16* ag[2]; _Float16* al[2][2];
#pragma unroll
  for (int s = 0; s < 2; s++) {
    int row = w * 32 + s * 16 + l4;
    int u = lu ^ ((row >> 1) & 3);
    ag[s] = act + ((long)z * CAPP + m0 + row) * HDIM + u * 8;
    al[0][s] = As + row * 32 + lu * 8;
    al[1][s] = al[0][s] + 128 * 32;
  }
  const _Float16* bg[2]; _Float16* bl[2][2];
#pragma unroll
  for (int s = 0; s < 2; s++) {
    int rb = w * 32 + s * 16 + l4;
    int u = lu ^ ((rb >> 1) & 3);
    bg[s] = w2t + ((long)e * DDIM + n0 + rb) * HDIM + u * 8;
    bl[0][s] = Bs + rb * 32 + lu * 8;
    bl[1][s] = bl[0][s] + 128 * 32;
  }

  int q = lane >> 4, m16 = lane & 15;
  int wm = w & 1, wn = w >> 1;

  f4 zero4 = {0.f, 0.f, 0.f, 0.f};
  f4 acc[4][4];
#pragma unroll
  for (int rt = 0; rt < 4; rt++)
#pragma unroll
    for (int ct = 0; ct < 4; ct++) acc[rt][ct] = zero4;

#pragma unroll
  for (int s = 0; s < 2; s++) { gld16(ag[s], al[0][s]); ag[s] += 32; }
#pragma unroll
  for (int s = 0; s < 2; s++) { gld16(bg[s], bl[0][s]); bg[s] += 32; }

  for (int kk = 0; kk < HDIM; kk += 32) {
    int cur = (kk >> 5) & 1, nxt = cur ^ 1;
    if (kk + 32 < HDIM) {
#pragma unroll
      for (int s = 0; s < 2; s++) { gld16(ag[s], al[nxt][s]); ag[s] += 32; }
#pragma unroll
      for (int s = 0; s < 2; s++) { gld16(bg[s], bl[nxt][s]); bg[s] += 32; }
      asm volatile("s_waitcnt vmcnt(4)" ::: "memory");
    } else {
      asm volatile("s_waitcnt vmcnt(0)" ::: "memory");
    }
    RAW_BARRIER();

    const _Float16* Ac = As + cur * 128 * 32;
    const _Float16* Bc = Bs + cur * 128 * 32;
    half8 af[4], bf[4];
#pragma unroll
    for (int rt = 0; rt < 4; rt++) {
      int row = wm * 64 + rt * 16 + m16;
      af[rt] = *(const half8*)(Ac + row * 32 + (q ^ ((row >> 1) & 3)) * 8);
    }
#pragma unroll
    for (int ct = 0; ct < 4; ct++) {
      int c = wn * 64 + ct * 16 + m16;
      bf[ct] = *(const half8*)(Bc + c * 32 + (q ^ ((c >> 1) & 3)) * 8);
    }
#pragma unroll
    for (int rt = 0; rt < 4; rt++)
#pragma unroll
      for (int ct = 0; ct < 4; ct++)
        acc[rt][ct] = __builtin_amdgcn_mfma_f32_16x16x32_f16(af[rt], bf[ct], acc[rt][ct], 0, 0, 0);
    RAW_BARRIER();
  }

  long yb = (long)z * CAPP * DDIM;
#pragma unroll
  for (int rt = 0; rt < 4; rt++)
#pragma unroll
    for (int ct = 0; ct < 4; ct++)
#pragma unroll
      for (int r = 0; r < 4; r++) {
        int row = m0 + wm * 64 + rt * 16 + q * 4 + r;
        int col = n0 + wn * 64 + ct * 16 + m16;
        ybuf[yb + (long)row * DDIM + col] = acc[rt][ct][r];
      }
}

// -------------------- gather --------------------
__global__ __launch_bounds__(256) void gather_kernel(const float* __restrict__ ybuf,
                                                     const int* __restrict__ tokpos,
                                                     const float* __restrict__ wts,
                                                     float* __restrict__ out) {
  int gid = blockIdx.x * 256 + threadIdx.x;
  int row = gid / 192, seg = gid % 192;
  f4 o = {0.f, 0.f, 0.f, 0.f};
#pragma unroll
  for (int k = 0; k < 2; k++) {
    int p = tokpos[k * N_TOK + row];
    if (p >= 0) {
      float wv = wts[row * 2 + k];
      f4 y = *(const f4*)(ybuf + (long)p * DDIM + seg * 4);
      o[0] += wv * y[0]; o[1] += wv * y[1]; o[2] += wv * y[2]; o[3] += wv * y[3];
    }
  }
  *(f4*)(out + (long)row * DDIM + seg * 4) = o;
}

// -------------------- launch --------------------

extern "C" void kernel_launch(void* const* d_in, const int* in_sizes, int n_in,
                              void* d_out, int out_size, void* d_ws, size_t ws_size,
                              hipStream_t stream) {
  const float* x  = (const float*)d_in[0];
  const float* Wg = (const float*)d_in[1];
  const float* W1 = (const float*)d_in[2];
  const float* W2 = (const float*)d_in[3];
  float* out = (float*)d_out;
  char* ws = (char*)d_ws;

  _Float16* xh   = (_Float16*)(ws + XH_OFF);
  _Float16* w1t  = (_Float16*)(ws + W1T_OFF);
  _Float16* w2t  = (_Float16*)(ws + W2T_OFF);
  _Float16* actb = (_Float16*)(ws + ACT_OFF);
  float* ybuf    = (float*)(ws + YBUF_OFF);
  int* eidx      = (int*)(ws + EIDX_OFF);
  float* wts     = (float*)(ws + WTS_OFF);
  int* toklist   = (int*)(ws + TOKL_OFF);
  int* tokpos    = (int*)(ws + TOKP_OFF);
  int* counts    = (int*)(ws + CNT_OFF);

  cvt_x_kernel<<<3073, 256, 0, stream>>>(x, xh);
  cvt_tr_kernel<<<dim3(12, 64, 8), 256, 0, stream>>>(W1, w1t, 768, 4096);
  cvt_tr_kernel<<<dim3(32, 12, 8), 256, 0, stream>>>(W2, w2t, 2048, 768);
  router_kernel<<<1024, 256, 0, stream>>>(x, Wg, eidx, wts);
  scan_kernel<<<1, 1024, 0, stream>>>(eidx, toklist, tokpos, counts);
  gemm1_kernel<<<1280, 256, 0, stream>>>(xh, w1t, toklist, counts, actb);
  gemm2_kernel<<<480, 256, 0, stream>>>(actb, w2t, counts, ybuf);
  gather_kernel<<<3072, 256, 0, stream>>>(ybuf, tokpos, wts, out);
}

// Round 4
// 346.280 us; speedup vs baseline: 1.1459x; 1.1459x over previous
//
#include <hip/hip_runtime.h>

// GatedMoE on MI355X (gfx950), fp16 MFMA path, round 4.
// vs r3: BK=64 single-buffered GEMMs (half the barriers), gemm2 fuses the
// weighted scatter via atomicAdd into out (ybuf+gather deleted), gemm2 at
// 3 waves/SIMD, LDS-tile cvt_tr (both sides coalesced), cvt_x fused into
// router, scan parallelized to 16 blocks.

typedef _Float16 half8 __attribute__((ext_vector_type(8)));
typedef _Float16 half4t __attribute__((ext_vector_type(4)));
typedef float f4 __attribute__((ext_vector_type(4)));

#define N_TOK 4096
#define DDIM  768
#define HDIM  2048
#define NEXP  8
#define CAP   614   // int(1.2 * 4096 / 8)
#define CAPP  640

// ---- workspace layout (bytes) ----
#define XH_OFF    0L           // (4097*768) fp16
#define W1T_OFF   6292992L     // [8][4096][768] fp16
#define W2T_OFF   56624640L    // [8][768][2048] fp16
#define ACT_OFF   81790464L    // [16][640][2048] fp16
#define EIDX_OFF  123733504L   // [4096][2] int
#define WTS_OFF   123766272L   // [4096][2] float
#define TOKL_OFF  123799040L   // [16][640] int
#define CNT_OFF   123840000L   // [16] int

__device__ __forceinline__ void gld16(const void* g, void* l) {
  __builtin_amdgcn_global_load_lds(
      (const __attribute__((address_space(1))) unsigned int*)g,
      (__attribute__((address_space(3))) unsigned int*)l, 16, 0, 0);
}

// -------------------- transpose+convert --------------------
// src fp32 [e][R][C] -> dst fp16 [e][C][R]. 64x64 tile through LDS:
// reads float4-coalesced, writes half8 (128B bursts per 8 lanes).
__global__ __launch_bounds__(256) void cvt_tr_kernel(const float* __restrict__ src,
                                                     _Float16* __restrict__ dst,
                                                     int R, int C) {
  __shared__ float tile[64 * 69];   // pad 69: <=2-way banks both phases
  int e = blockIdx.z;
  int r0 = blockIdx.x * 64, c0 = blockIdx.y * 64;
  long sb = (long)e * R * C;
  int t = threadIdx.x;
  int rrow = t >> 4, c4 = (t & 15) * 4;
#pragma unroll
  for (int i = 0; i < 4; i++) {
    int row = i * 16 + rrow;
    f4 v = *(const f4*)(src + sb + (long)(r0 + row) * C + c0 + c4);
    *(f4*)(&tile[row * 69 + c4]) = v;
  }
  __syncthreads();
#pragma unroll
  for (int s = 0; s < 2; s++) {
    int idx = t + s * 256;
    int c = idx >> 3, ch = idx & 7;
    half8 h;
#pragma unroll
    for (int j = 0; j < 8; j++) h[j] = (_Float16)tile[(ch * 8 + j) * 69 + c];
    *(half8*)(dst + sb + (long)(c0 + c) * R + r0 + ch * 8) = h;
  }
}

// -------------------- router (+ x->fp16 convert) --------------------
__global__ __launch_bounds__(256) void router_kernel(const float* __restrict__ x,
                                                     const float* __restrict__ Wg,
                                                     _Float16* __restrict__ xh,
                                                     int* __restrict__ eidx,
                                                     float* __restrict__ wts) {
  __shared__ float wg[DDIM * NEXP];
  int t = threadIdx.x;
  for (int i = t; i < DDIM * NEXP; i += 256) wg[i] = Wg[i];
  __syncthreads();
  int w = t >> 6, lane = t & 63;
  int tok = blockIdx.x * 4 + w;
  if (tok > N_TOK) return;
  if (tok == N_TOK) {           // zero pad row
    half4t zz; zz[0] = zz[1] = zz[2] = zz[3] = (_Float16)0.f;
#pragma unroll
    for (int j = 0; j < 3; j++) *(half4t*)(xh + (long)N_TOK * DDIM + (lane + j * 64) * 4) = zz;
    return;
  }
  const float* xr = x + (long)tok * DDIM;
  // fp16 convert (vectorized re-read, L2-hot)
#pragma unroll
  for (int j = 0; j < 3; j++) {
    f4 v = *(const f4*)(xr + (lane + j * 64) * 4);
    half4t hv;
    hv[0] = (_Float16)v[0]; hv[1] = (_Float16)v[1];
    hv[2] = (_Float16)v[2]; hv[3] = (_Float16)v[3];
    *(half4t*)(xh + (long)tok * DDIM + (lane + j * 64) * 4) = hv;
  }
  float acc[8] = {0.f, 0.f, 0.f, 0.f, 0.f, 0.f, 0.f, 0.f};
#pragma unroll
  for (int i = 0; i < 12; i++) {
    float xv = xr[i * 64 + lane];
    const float* wr = &wg[(i * 64 + lane) * 8];
#pragma unroll
    for (int e2 = 0; e2 < 8; e2++) acc[e2] += xv * wr[e2];
  }
#pragma unroll
  for (int e2 = 0; e2 < 8; e2++) {
    float v = acc[e2];
    v += __shfl_xor(v, 32); v += __shfl_xor(v, 16); v += __shfl_xor(v, 8);
    v += __shfl_xor(v, 4);  v += __shfl_xor(v, 2);  v += __shfl_xor(v, 1);
    acc[e2] = v;
  }
  if (lane == 0) {
    float m0 = -1e30f; int i0 = 0;
#pragma unroll
    for (int e2 = 0; e2 < 8; e2++) if (acc[e2] > m0) { m0 = acc[e2]; i0 = e2; }
    float m1 = -1e30f; int i1 = 0;
#pragma unroll
    for (int e2 = 0; e2 < 8; e2++) if (e2 != i0 && acc[e2] > m1) { m1 = acc[e2]; i1 = e2; }
    float tt = __expf(m1 - m0);
    float w0 = 1.f / (1.f + tt);
    eidx[tok * 2 + 0] = i0; eidx[tok * 2 + 1] = i1;
    wts[tok * 2 + 0] = w0;  wts[tok * 2 + 1] = 1.f - w0;
  }
}

// -------------------- capacity scan (16 blocks, one per (k,e)) --------------------
__global__ __launch_bounds__(64) void scan_kernel(const int* __restrict__ eidx,
                                                  int* __restrict__ toklist,
                                                  int* __restrict__ counts) {
  int z = blockIdx.x;
  int k = z >> 3, e = z & 7;
  int lane = threadIdx.x;
  int mye[64];
#pragma unroll
  for (int c = 0; c < 64; c++) mye[c] = eidx[(c * 64 + lane) * 2 + k];
  int base = 0;
#pragma unroll 4
  for (int c = 0; c < 64; c++) {
    int n = c * 64 + lane;
    bool pred = (mye[c] == e);
    unsigned long long mask = __ballot(pred);
    if (pred) {
      int pos = base + __popcll(mask & ((1ull << lane) - 1ull));
      if (pos < CAP) toklist[z * CAPP + pos] = n;
    }
    base += __popcll(mask);
  }
  if (lane == 0) counts[z] = (base < CAP) ? base : CAP;
}

// -------------------- GEMM1 + fused SwiGLU --------------------
// Tile 128 tokens x 128 act cols (256 B rows: h1+h2), BK=64, single-buffered.
__global__ __launch_bounds__(256, 2) void gemm1_kernel(const _Float16* __restrict__ xh,
                                                       const _Float16* __restrict__ w1t,
                                                       const int* __restrict__ toklist,
                                                       const int* __restrict__ counts,
                                                       _Float16* __restrict__ act) {
  int i = blockIdx.x;
  int xcd = i & 7, j = i >> 3;       // 1280 blocks, 160/xcd
  int m = j % 5, ii = j / 5;
  int k = ii & 1, n = ii >> 1;
  int e = xcd, z = k * 8 + e;
  int count = counts[z];
  int m0 = m * 128;
  if (m0 >= count) return;
  int n0 = n * 128;

  __shared__ _Float16 As[128 * 64];   // 16 KB
  __shared__ _Float16 Bs[256 * 64];   // 32 KB
  __shared__ int toks[128];

  int t = threadIdx.x;
  if (t < 128) {
    int r = m0 + t;
    toks[t] = (r < count) ? toklist[z * CAPP + r] : N_TOK;   // pad -> zero row
  }
  __syncthreads();

  int lane = t & 63, w = t >> 6;
  int l8 = lane >> 3, u8 = lane & 7;

  // A: 4 sweeps of 8 rows/wave; B: 8 sweeps. Global side carries the XOR swizzle.
  const _Float16* ag[4]; _Float16* al[4];
#pragma unroll
  for (int s = 0; s < 4; s++) {
    int row = w * 32 + s * 8 + l8;
    ag[s] = xh + (long)toks[row] * DDIM + ((u8 ^ (row & 7)) * 8);
    al[s] = As + row * 64 + u8 * 8;
  }
  const _Float16* bg[8]; _Float16* bl[8];
#pragma unroll
  for (int s = 0; s < 8; s++) {
    int rb = w * 64 + s * 8 + l8;
    int gr = (rb < 128) ? (n0 + rb) : (2048 + n0 + (rb - 128));
    bg[s] = w1t + ((long)e * 4096 + gr) * DDIM + ((u8 ^ (rb & 7)) * 8);
    bl[s] = Bs + rb * 64 + u8 * 8;
  }

  int q = lane >> 4, m16 = lane & 15;
  int wm = w & 1, wn = w >> 1;

  f4 zero4 = {0.f, 0.f, 0.f, 0.f};
  f4 acc[4][4][2];
#pragma unroll
  for (int rt = 0; rt < 4; rt++)
#pragma unroll
    for (int ct = 0; ct < 4; ct++) { acc[rt][ct][0] = zero4; acc[rt][ct][1] = zero4; }

  for (int kk = 0; kk < DDIM; kk += 64) {
    __syncthreads();
#pragma unroll
    for (int s = 0; s < 4; s++) { gld16(ag[s], al[s]); ag[s] += 64; }
#pragma unroll
    for (int s = 0; s < 8; s++) { gld16(bg[s], bl[s]); bg[s] += 64; }
    __syncthreads();

#pragma unroll
    for (int c = 0; c < 2; c++) {
      half8 af[4], bf[4][2];
#pragma unroll
      for (int rt = 0; rt < 4; rt++) {
        int row = wm * 64 + rt * 16 + m16;
        af[rt] = *(const half8*)(As + row * 64 + (((c * 4 + q) ^ (row & 7)) * 8));
      }
#pragma unroll
      for (int ct = 0; ct < 4; ct++) {
        int cb = wn * 64 + ct * 16 + m16;
        int ph = ((c * 4 + q) ^ (cb & 7)) * 8;    // (cb+128)&7 == cb&7
        bf[ct][0] = *(const half8*)(Bs + cb * 64 + ph);
        bf[ct][1] = *(const half8*)(Bs + (128 + cb) * 64 + ph);
      }
#pragma unroll
      for (int rt = 0; rt < 4; rt++)
#pragma unroll
        for (int ct = 0; ct < 4; ct++) {
          acc[rt][ct][0] = __builtin_amdgcn_mfma_f32_16x16x32_f16(af[rt], bf[ct][0], acc[rt][ct][0], 0, 0, 0);
          acc[rt][ct][1] = __builtin_amdgcn_mfma_f32_16x16x32_f16(af[rt], bf[ct][1], acc[rt][ct][1], 0, 0, 0);
        }
    }
  }

  long ab = (long)z * CAPP * HDIM;
#pragma unroll
  for (int rt = 0; rt < 4; rt++)
#pragma unroll
    for (int ct = 0; ct < 4; ct++)
#pragma unroll
      for (int r = 0; r < 4; r++) {
        int row = m0 + wm * 64 + rt * 16 + q * 4 + r;   // C/D: row = quad*4+reg
        int col = n0 + wn * 64 + ct * 16 + m16;         //      col = lane&15
        float h1 = acc[rt][ct][0][r], h2 = acc[rt][ct][1][r];
        float s = h2 / (1.f + __expf(-h2));
        act[ab + (long)row * HDIM + col] = (_Float16)(h1 * s);
      }
}

// -------------------- GEMM2 + weighted scatter (atomicAdd into out) --------------------
__global__ __launch_bounds__(256, 3) void gemm2_kernel(const _Float16* __restrict__ act,
                                                       const _Float16* __restrict__ w2t,
                                                       const int* __restrict__ toklist,
                                                       const int* __restrict__ counts,
                                                       const float* __restrict__ wts,
                                                       float* __restrict__ out) {
  int i = blockIdx.x;
  int xcd = i & 7, j = i >> 3;       // 480 blocks, 60/xcd
  int m = j % 5, t2 = j / 5;         // t2<12: k=t2&1, n=t2>>1 (0..5)
  int k = t2 & 1, n = t2 >> 1;
  int e = xcd, z = k * 8 + e;
  int count = counts[z];
  int m0 = m * 128;
  if (m0 >= count) return;
  int n0 = n * 128;

  __shared__ _Float16 As[128 * 64];   // 16 KB
  __shared__ _Float16 Bs[128 * 64];   // 16 KB
  __shared__ int toksL[128];
  __shared__ float wrow[128];

  int t = threadIdx.x;
  if (t < 128) {
    int r = m0 + t;
    if (r < count) {
      int tok = toklist[z * CAPP + r];
      toksL[t] = tok;
      wrow[t] = wts[tok * 2 + k];
    } else {
      toksL[t] = -1;
      wrow[t] = 0.f;
    }
  }
  __syncthreads();

  int lane = t & 63, w = t >> 6;
  int l8 = lane >> 3, u8 = lane & 7;

  const _Float16* ag[4]; _Float16* al[4];
#pragma unroll
  for (int s = 0; s < 4; s++) {
    int row = w * 32 + s * 8 + l8;
    ag[s] = act + ((long)z * CAPP + m0 + row) * HDIM + ((u8 ^ (row & 7)) * 8);
    al[s] = As + row * 64 + u8 * 8;
  }
  const _Float16* bg[4]; _Float16* bl[4];
#pragma unroll
  for (int s = 0; s < 4; s++) {
    int rb = w * 32 + s * 8 + l8;
    bg[s] = w2t + ((long)e * DDIM + n0 + rb) * HDIM + ((u8 ^ (rb & 7)) * 8);
    bl[s] = Bs + rb * 64 + u8 * 8;
  }

  int q = lane >> 4, m16 = lane & 15;
  int wm = w & 1, wn = w >> 1;

  f4 zero4 = {0.f, 0.f, 0.f, 0.f};
  f4 acc[4][4];
#pragma unroll
  for (int rt = 0; rt < 4; rt++)
#pragma unroll
    for (int ct = 0; ct < 4; ct++) acc[rt][ct] = zero4;

  for (int kk = 0; kk < HDIM; kk += 64) {
    __syncthreads();
#pragma unroll
    for (int s = 0; s < 4; s++) { gld16(ag[s], al[s]); ag[s] += 64; }
#pragma unroll
    for (int s = 0; s < 4; s++) { gld16(bg[s], bl[s]); bg[s] += 64; }
    __syncthreads();

#pragma unroll
    for (int c = 0; c < 2; c++) {
      half8 af[4], bf[4];
#pragma unroll
      for (int rt = 0; rt < 4; rt++) {
        int row = wm * 64 + rt * 16 + m16;
        af[rt] = *(const half8*)(As + row * 64 + (((c * 4 + q) ^ (row & 7)) * 8));
      }
#pragma unroll
      for (int ct = 0; ct < 4; ct++) {
        int cb = wn * 64 + ct * 16 + m16;
        bf[ct] = *(const half8*)(Bs + cb * 64 + (((c * 4 + q) ^ (cb & 7)) * 8));
      }
#pragma unroll
      for (int rt = 0; rt < 4; rt++)
#pragma unroll
        for (int ct = 0; ct < 4; ct++)
          acc[rt][ct] = __builtin_amdgcn_mfma_f32_16x16x32_f16(af[rt], bf[ct], acc[rt][ct], 0, 0, 0);
    }
  }

  // weighted scatter: out[tok, col] += w * y
#pragma unroll
  for (int rt = 0; rt < 4; rt++)
#pragma unroll
    for (int ct = 0; ct < 4; ct++)
#pragma unroll
      for (int r = 0; r < 4; r++) {
        int lr = wm * 64 + rt * 16 + q * 4 + r;
        int tok = toksL[lr];
        if (tok >= 0) {
          int col = n0 + wn * 64 + ct * 16 + m16;
          atomicAdd(&out[(long)tok * DDIM + col], wrow[lr] * acc[rt][ct][r]);
        }
      }
}

// -------------------- launch --------------------

extern "C" void kernel_launch(void* const* d_in, const int* in_sizes, int n_in,
                              void* d_out, int out_size, void* d_ws, size_t ws_size,
                              hipStream_t stream) {
  const float* x  = (const float*)d_in[0];
  const float* Wg = (const float*)d_in[1];
  const float* W1 = (const float*)d_in[2];
  const float* W2 = (const float*)d_in[3];
  float* out = (float*)d_out;
  char* ws = (char*)d_ws;

  _Float16* xh   = (_Float16*)(ws + XH_OFF);
  _Float16* w1t  = (_Float16*)(ws + W1T_OFF);
  _Float16* w2t  = (_Float16*)(ws + W2T_OFF);
  _Float16* actb = (_Float16*)(ws + ACT_OFF);
  int* eidx      = (int*)(ws + EIDX_OFF);
  float* wts     = (float*)(ws + WTS_OFF);
  int* toklist   = (int*)(ws + TOKL_OFF);
  int* counts    = (int*)(ws + CNT_OFF);

  hipMemsetAsync(d_out, 0, (size_t)out_size * sizeof(float), stream);
  cvt_tr_kernel<<<dim3(12, 64, 8), 256, 0, stream>>>(W1, w1t, 768, 4096);
  cvt_tr_kernel<<<dim3(32, 12, 8), 256, 0, stream>>>(W2, w2t, 2048, 768);
  router_kernel<<<1025, 256, 0, stream>>>(x, Wg, xh, eidx, wts);
  scan_kernel<<<16, 64, 0, stream>>>(eidx, toklist, counts);
  gemm1_kernel<<<1280, 256, 0, stream>>>(xh, w1t, toklist, counts, actb);
  gemm2_kernel<<<480, 256, 0, stream>>>(actb, w2t, toklist, counts, wts, out);
}